// Round 9
// baseline (207.682 us; speedup 1.0000x reference)
//
#include <hip/hip_runtime.h>
#include <hip/hip_cooperative_groups.h>

namespace cg = cooperative_groups;

namespace {
constexpr float GRIDSZ = 0.4f;
constexpr float PCXY = -40.0f;   // pc_min.x == pc_min.y
constexpr float PCZ  = -1.0f;
constexpr int CCH = 18;          // semantic channels
constexpr int CELLS_X = 25;      // 200 voxels / 8 per xy-cell (z not binned)
constexpr int NCELLS = CELLS_X * CELLS_X;  // 625
constexpr int VMAX = 199;        // max voxel index in x,y
constexpr int PCAP = 128;        // per-cell point cap (mean ~26)
constexpr int GCAP = 128;        // per-cell candidate cap (mean ~28)
constexpr int SEMW = 20;         // padded semantic row in LDS (80 B)
}

// ---------- shared device helpers ----------
__device__ __forceinline__ void gauss_cellbox(float mx, float my, float smax,
                                              int& cx0, int& cx1, int& cy0, int& cy1) {
  // must match numpy floor((x-pc_min)/GRID) in f32 exactly
  int mvx = (int)floorf((mx - PCXY) / GRIDSZ);
  int mvy = (int)floorf((my - PCXY) / GRIDSZ);
  int r = (int)ceilf(smax * 3.0f / GRIDSZ);
  cx0 = max(mvx - r, 0) >> 3; cx1 = min(mvx + r, VMAX) >> 3;
  cy0 = max(mvy - r, 0) >> 3; cy1 = min(mvy + r, VMAX) >> 3;
}

// ================= cooperative single-kernel path =================
// Phase -1: zero counters. sync. Phase 0: scatter point/gaussian indices into
// per-cell lists (device atomics). fence+sync. Phase 1: each block consumes
// exactly its own cell's lists — no scan anywhere.
__global__ __launch_bounds__(256) void coop_kernel(
    const float* __restrict__ pts, const float* __restrict__ means,
    const float* __restrict__ opac, const float* __restrict__ scales,
    const float* __restrict__ cov, const float* __restrict__ sem,
    float* __restrict__ out, int* __restrict__ cnt,
    unsigned short* __restrict__ plist, unsigned short* __restrict__ glist,
    int N, int M) {
  __shared__ int lpi[PCAP];
  __shared__ int lvox[PCAP];
  __shared__ float4 lpts[PCAP];
  __shared__ int graw[GCAP];
  __shared__ int gsrt[GCAP];
  __shared__ int4 lbox[GCAP];
  __shared__ float4 lpay[GCAP * 3];
  __shared__ float lsem[GCAP * SEMW];
  __shared__ float buf[3][64][CCH + 1];  // +1 pad -> 19-word lane stride

  cg::grid_group grid = cg::this_grid();
  const int tid = threadIdx.x, lane = tid & 63, wave = tid >> 6;
  const int cell = blockIdx.x;
  const int gid = blockIdx.x * 256 + tid;

  // Phase -1: zero the 2*NCELLS counters.
  if (gid < 2 * NCELLS) cnt[gid] = 0;
  __threadfence();
  grid.sync();

  // Phase 0: build per-cell index lists (ushort indices only).
  if (gid < M) {
    int g = gid;
    float mx = means[(size_t)g * 3 + 0], my = means[(size_t)g * 3 + 1];
    float smax = fmaxf(scales[(size_t)g * 3 + 0],
                 fmaxf(scales[(size_t)g * 3 + 1], scales[(size_t)g * 3 + 2]));
    int cx0, cx1, cy0, cy1;
    gauss_cellbox(mx, my, smax, cx0, cx1, cy0, cy1);
    for (int cyy = cy0; cyy <= cy1; ++cyy)
      for (int cxx = cx0; cxx <= cx1; ++cxx) {
        int cl = cxx + CELLS_X * cyy;
        int s = atomicAdd(&cnt[NCELLS + cl], 1);
        if (s < GCAP) glist[cl * GCAP + s] = (unsigned short)g;
      }
  } else if (gid < M + N) {
    int p = gid - M;
    float px = pts[(size_t)p * 3 + 0], py = pts[(size_t)p * 3 + 1];
    int pvx = (int)floorf((px - PCXY) / GRIDSZ);
    int pvy = (int)floorf((py - PCXY) / GRIDSZ);
    int cl = (pvx >> 3) + CELLS_X * (pvy >> 3);
    int s = atomicAdd(&cnt[cl], 1);
    if (s < PCAP) plist[cl * PCAP + s] = (unsigned short)p;
  }
  __threadfence();
  grid.sync();

  // Phase 1: per-cell aggregation from own lists.
  const int P = min(cnt[cell], PCAP);
  const int K = min(cnt[NCELLS + cell], GCAP);

  if (tid < P) lpi[tid] = (int)plist[cell * PCAP + tid];
  if (tid < K) graw[tid] = (int)glist[cell * GCAP + tid];
  __syncthreads();
  // rank-sort candidates ascending: deterministic accumulation order
  if (tid < K) {
    int v = graw[tid], rank = 0;
    for (int j = 0; j < K; ++j) rank += (graw[j] < v);
    gsrt[rank] = v;
  }
  __syncthreads();

  // Survivor payload build (exact IEEE ops, identical to reference).
  if (tid < P) {
    int i = lpi[tid];
    float px = pts[(size_t)i * 3], py = pts[(size_t)i * 3 + 1], pz = pts[(size_t)i * 3 + 2];
    int pvx = (int)floorf((px - PCXY) / GRIDSZ);
    int pvy = (int)floorf((py - PCXY) / GRIDSZ);
    int pvz = (int)floorf((pz - PCZ) / GRIDSZ);
    lvox[tid] = pvx | (pvy << 8) | (pvz << 16);
    lpts[tid] = make_float4(px, py, pz, __int_as_float(i));
  } else if (tid >= 128 && tid - 128 < K) {
    int t = tid - 128;
    int g = gsrt[t];
    float mx = means[(size_t)g * 3], my = means[(size_t)g * 3 + 1], mz = means[(size_t)g * 3 + 2];
    int mvx = (int)floorf((mx - PCXY) / GRIDSZ);
    int mvy = (int)floorf((my - PCXY) / GRIDSZ);
    int mvz = (int)floorf((mz - PCZ) / GRIDSZ);
    float sm = fmaxf(scales[(size_t)g * 3],
               fmaxf(scales[(size_t)g * 3 + 1], scales[(size_t)g * 3 + 2]));
    int r = (int)ceilf(sm * 3.0f / GRIDSZ);
    lbox[t] = make_int4(mvx - r, mvy - r, mvz - r, 2 * r);
    const float* c = cov + (size_t)g * 9;
    float c00 = c[0], c01 = c[1], c02 = c[2], c11 = c[4], c12 = c[5], c22 = c[8];
    float M00 = c11 * c22 - c12 * c12;
    float M01 = c02 * c12 - c01 * c22;
    float M02 = c01 * c12 - c02 * c11;
    float inv = 1.0f / (c00 * M00 + c01 * M01 + c02 * M02);
    lpay[t * 3 + 0] = make_float4(mx, my, mz, opac[g]);
    lpay[t * 3 + 1] = make_float4(M00 * inv, M01 * inv, M02 * inv,
                                  (c00 * c22 - c02 * c02) * inv);
    lpay[t * 3 + 2] = make_float4((c01 * c02 - c00 * c12) * inv,
                                  (c00 * c11 - c01 * c01) * inv, 0.f, 0.f);
  }
  for (int idx = tid; idx < K * CCH; idx += 256) {
    int j = idx / CCH, c2 = idx - j * CCH;
    lsem[j * SEMW + c2] = sem[(size_t)gsrt[j] * CCH + c2];
  }
  __syncthreads();

  // Dense point x candidate loop, wave-quartered (deterministic order).
  const int kq = (K + 3) >> 2;
  const int j0 = wave * kq, j1 = min(K, j0 + kq);

  for (int pb = 0; pb < P; pb += 64) {
    const bool vp = (pb + lane) < P;
    const float4 pt = lpts[vp ? pb + lane : 0];
    const int pv = vp ? lvox[pb + lane] : 0;
    int pvx = vp ? (pv & 255) : -100000;  // sentinel fails every box
    int pvy = (pv >> 8) & 255;
    int pvz = pv >> 16;

    float acc[CCH];
#pragma unroll
    for (int c = 0; c < CCH; ++c) acc[c] = 0.f;

    for (int j = j0; j < j1; ++j) {
      int4 bx = lbox[j];  // uniform -> LDS broadcast
      bool m = ((unsigned)(pvx - bx.x) <= (unsigned)bx.w) &
               ((unsigned)(pvy - bx.y) <= (unsigned)bx.w) &
               ((unsigned)(pvz - bx.z) <= (unsigned)bx.w);
      if (__any(m)) {
        float4 q0 = lpay[j * 3 + 0];
        float4 q1 = lpay[j * 3 + 1];
        float4 q2 = lpay[j * 3 + 2];
        float dx = pt.x - q0.x, dy = pt.y - q0.y, dz = pt.z - q0.z;
        float t0 = q1.x * dx + q1.y * dy + q1.z * dz;
        float t1 = q1.y * dx + q1.w * dy + q2.x * dz;
        float t2 = q1.z * dx + q2.x * dy + q2.y * dz;
        float qq = dx * t0 + dy * t1 + dz * t2;
        float w = m ? __expf(-0.5f * qq) * q0.w : 0.f;
        const float4* s4 = reinterpret_cast<const float4*>(&lsem[j * SEMW]);
        float4 sa = s4[0], sb = s4[1], sc = s4[2], sd = s4[3];
        float2 se = *reinterpret_cast<const float2*>(&lsem[j * SEMW + 16]);
        acc[0]  = fmaf(w, sa.x, acc[0]);  acc[1]  = fmaf(w, sa.y, acc[1]);
        acc[2]  = fmaf(w, sa.z, acc[2]);  acc[3]  = fmaf(w, sa.w, acc[3]);
        acc[4]  = fmaf(w, sb.x, acc[4]);  acc[5]  = fmaf(w, sb.y, acc[5]);
        acc[6]  = fmaf(w, sb.z, acc[6]);  acc[7]  = fmaf(w, sb.w, acc[7]);
        acc[8]  = fmaf(w, sc.x, acc[8]);  acc[9]  = fmaf(w, sc.y, acc[9]);
        acc[10] = fmaf(w, sc.z, acc[10]); acc[11] = fmaf(w, sc.w, acc[11]);
        acc[12] = fmaf(w, sd.x, acc[12]); acc[13] = fmaf(w, sd.y, acc[13]);
        acc[14] = fmaf(w, sd.z, acc[14]); acc[15] = fmaf(w, sd.w, acc[15]);
        acc[16] = fmaf(w, se.x, acc[16]); acc[17] = fmaf(w, se.y, acc[17]);
      }
    }

    if (wave > 0) {
#pragma unroll
      for (int c = 0; c < CCH; ++c) buf[wave - 1][lane][c] = acc[c];
    }
    __syncthreads();
    if (wave == 0 && vp) {
      int myp = __float_as_int(pt.w);
      float* o = out + (size_t)myp * CCH;
#pragma unroll
      for (int c = 0; c < CCH; ++c)
        o[c] = acc[c] + buf[0][lane][c] + buf[1][lane][c] + buf[2][lane][c];
    }
    __syncthreads();
  }
}

// ================= fallback: proven R8 two-kernel path =================
__global__ __launch_bounds__(256) void prep_kernel(
    const float* __restrict__ pts, const float* __restrict__ means,
    const float* __restrict__ scales,
    unsigned short* __restrict__ pcell, unsigned* __restrict__ gcb,
    int N, int M) {
  int id = blockIdx.x * 256 + threadIdx.x;
  if (id < M) {
    int g = id;
    float mx = means[(size_t)g * 3 + 0], my = means[(size_t)g * 3 + 1];
    float smax = fmaxf(scales[(size_t)g * 3 + 0],
                 fmaxf(scales[(size_t)g * 3 + 1], scales[(size_t)g * 3 + 2]));
    int cx0, cx1, cy0, cy1;
    gauss_cellbox(mx, my, smax, cx0, cx1, cy0, cy1);
    gcb[g] = (unsigned)cx0 | ((unsigned)cx1 << 8) | ((unsigned)cy0 << 16) | ((unsigned)cy1 << 24);
  } else if (id < M + N) {
    int p = id - M;
    float px = pts[(size_t)p * 3 + 0], py = pts[(size_t)p * 3 + 1];
    int pvx = (int)floorf((px - PCXY) / GRIDSZ);
    int pvy = (int)floorf((py - PCXY) / GRIDSZ);
    pcell[p] = (unsigned short)((pvx >> 3) + CELLS_X * (pvy >> 3));
  }
}

__global__ __launch_bounds__(256) void agg_kernel(
    const float* __restrict__ pts, const float* __restrict__ means,
    const float* __restrict__ opac, const float* __restrict__ scales,
    const float* __restrict__ cov, const float* __restrict__ sem,
    const unsigned short* __restrict__ pcell, const unsigned* __restrict__ gcb,
    float* __restrict__ out, int N, int M) {
  __shared__ int pcnt_s, gcnt_s;
  __shared__ int lpi[PCAP];
  __shared__ int lvox[PCAP];
  __shared__ float4 lpts[PCAP];
  __shared__ int graw[GCAP];
  __shared__ int gsrt[GCAP];
  __shared__ int4 lbox[GCAP];
  __shared__ float4 lpay[GCAP * 3];
  __shared__ float lsem[GCAP * SEMW];
  __shared__ float buf[3][64][CCH + 1];

  const int tid = threadIdx.x, lane = tid & 63, wave = tid >> 6;
  const unsigned cellv = blockIdx.x;
  const int cx = (int)(cellv % CELLS_X), cy = (int)(cellv / CELLS_X);

  if (tid == 0) { pcnt_s = 0; gcnt_s = 0; }
  __syncthreads();

  {
    const uint4* pc4 = reinterpret_cast<const uint4*>(pcell);
    const int n8 = N >> 3;
    for (int i8 = tid; i8 < n8; i8 += 256) {
      uint4 v = pc4[i8];
      unsigned w[4] = {v.x, v.y, v.z, v.w};
#pragma unroll
      for (int k = 0; k < 4; ++k) {
        if ((w[k] & 0xFFFFu) == cellv) {
          int s = atomicAdd(&pcnt_s, 1);
          if (s < PCAP) lpi[s] = i8 * 8 + 2 * k;
        }
        if ((w[k] >> 16) == cellv) {
          int s = atomicAdd(&pcnt_s, 1);
          if (s < PCAP) lpi[s] = i8 * 8 + 2 * k + 1;
        }
      }
    }
    for (int i = (n8 << 3) + tid; i < N; i += 256) {
      if (pcell[i] == cellv) {
        int s = atomicAdd(&pcnt_s, 1);
        if (s < PCAP) lpi[s] = i;
      }
    }
  }
  {
    const uint4* gb4 = reinterpret_cast<const uint4*>(gcb);
    const int m4 = M >> 2;
    for (int i4 = tid; i4 < m4; i4 += 256) {
      uint4 v = gb4[i4];
      unsigned gk[4] = {v.x, v.y, v.z, v.w};
#pragma unroll
      for (int k = 0; k < 4; ++k) {
        unsigned pk = gk[k];
        bool hit = (cx >= (int)(pk & 255u)) & (cx <= (int)((pk >> 8) & 255u)) &
                   (cy >= (int)((pk >> 16) & 255u)) & (cy <= (int)(pk >> 24));
        if (hit) {
          int s = atomicAdd(&gcnt_s, 1);
          if (s < GCAP) graw[s] = i4 * 4 + k;
        }
      }
    }
    for (int g = (m4 << 2) + tid; g < M; g += 256) {
      unsigned pk = gcb[g];
      bool hit = (cx >= (int)(pk & 255u)) & (cx <= (int)((pk >> 8) & 255u)) &
                 (cy >= (int)((pk >> 16) & 255u)) & (cy <= (int)(pk >> 24));
      if (hit) {
        int s = atomicAdd(&gcnt_s, 1);
        if (s < GCAP) graw[s] = g;
      }
    }
  }
  __syncthreads();
  const int P = min(pcnt_s, PCAP);
  const int K = min(gcnt_s, GCAP);

  if (tid < K) {
    int v = graw[tid], rank = 0;
    for (int j = 0; j < K; ++j) rank += (graw[j] < v);
    gsrt[rank] = v;
  }
  __syncthreads();

  if (tid < P) {
    int i = lpi[tid];
    float px = pts[(size_t)i * 3], py = pts[(size_t)i * 3 + 1], pz = pts[(size_t)i * 3 + 2];
    int pvx = (int)floorf((px - PCXY) / GRIDSZ);
    int pvy = (int)floorf((py - PCXY) / GRIDSZ);
    int pvz = (int)floorf((pz - PCZ) / GRIDSZ);
    lvox[tid] = pvx | (pvy << 8) | (pvz << 16);
    lpts[tid] = make_float4(px, py, pz, __int_as_float(i));
  } else if (tid >= 128 && tid - 128 < K) {
    int t = tid - 128;
    int g = gsrt[t];
    float mx = means[(size_t)g * 3], my = means[(size_t)g * 3 + 1], mz = means[(size_t)g * 3 + 2];
    int mvx = (int)floorf((mx - PCXY) / GRIDSZ);
    int mvy = (int)floorf((my - PCXY) / GRIDSZ);
    int mvz = (int)floorf((mz - PCZ) / GRIDSZ);
    float sm = fmaxf(scales[(size_t)g * 3],
               fmaxf(scales[(size_t)g * 3 + 1], scales[(size_t)g * 3 + 2]));
    int r = (int)ceilf(sm * 3.0f / GRIDSZ);
    lbox[t] = make_int4(mvx - r, mvy - r, mvz - r, 2 * r);
    const float* c = cov + (size_t)g * 9;
    float c00 = c[0], c01 = c[1], c02 = c[2], c11 = c[4], c12 = c[5], c22 = c[8];
    float M00 = c11 * c22 - c12 * c12;
    float M01 = c02 * c12 - c01 * c22;
    float M02 = c01 * c12 - c02 * c11;
    float inv = 1.0f / (c00 * M00 + c01 * M01 + c02 * M02);
    lpay[t * 3 + 0] = make_float4(mx, my, mz, opac[g]);
    lpay[t * 3 + 1] = make_float4(M00 * inv, M01 * inv, M02 * inv,
                                  (c00 * c22 - c02 * c02) * inv);
    lpay[t * 3 + 2] = make_float4((c01 * c02 - c00 * c12) * inv,
                                  (c00 * c11 - c01 * c01) * inv, 0.f, 0.f);
  }
  for (int idx = tid; idx < K * CCH; idx += 256) {
    int j = idx / CCH, c2 = idx - j * CCH;
    lsem[j * SEMW + c2] = sem[(size_t)gsrt[j] * CCH + c2];
  }
  __syncthreads();

  const int kq = (K + 3) >> 2;
  const int j0 = wave * kq, j1 = min(K, j0 + kq);

  for (int pb = 0; pb < P; pb += 64) {
    const bool vp = (pb + lane) < P;
    const float4 pt = lpts[vp ? pb + lane : 0];
    const int pv = vp ? lvox[pb + lane] : 0;
    int pvx = vp ? (pv & 255) : -100000;
    int pvy = (pv >> 8) & 255;
    int pvz = pv >> 16;

    float acc[CCH];
#pragma unroll
    for (int c = 0; c < CCH; ++c) acc[c] = 0.f;

    for (int j = j0; j < j1; ++j) {
      int4 bx = lbox[j];
      bool m = ((unsigned)(pvx - bx.x) <= (unsigned)bx.w) &
               ((unsigned)(pvy - bx.y) <= (unsigned)bx.w) &
               ((unsigned)(pvz - bx.z) <= (unsigned)bx.w);
      if (__any(m)) {
        float4 q0 = lpay[j * 3 + 0];
        float4 q1 = lpay[j * 3 + 1];
        float4 q2 = lpay[j * 3 + 2];
        float dx = pt.x - q0.x, dy = pt.y - q0.y, dz = pt.z - q0.z;
        float t0 = q1.x * dx + q1.y * dy + q1.z * dz;
        float t1 = q1.y * dx + q1.w * dy + q2.x * dz;
        float t2 = q1.z * dx + q2.x * dy + q2.y * dz;
        float qq = dx * t0 + dy * t1 + dz * t2;
        float w = m ? __expf(-0.5f * qq) * q0.w : 0.f;
        const float4* s4 = reinterpret_cast<const float4*>(&lsem[j * SEMW]);
        float4 sa = s4[0], sb = s4[1], sc = s4[2], sd = s4[3];
        float2 se = *reinterpret_cast<const float2*>(&lsem[j * SEMW + 16]);
        acc[0]  = fmaf(w, sa.x, acc[0]);  acc[1]  = fmaf(w, sa.y, acc[1]);
        acc[2]  = fmaf(w, sa.z, acc[2]);  acc[3]  = fmaf(w, sa.w, acc[3]);
        acc[4]  = fmaf(w, sb.x, acc[4]);  acc[5]  = fmaf(w, sb.y, acc[5]);
        acc[6]  = fmaf(w, sb.z, acc[6]);  acc[7]  = fmaf(w, sb.w, acc[7]);
        acc[8]  = fmaf(w, sc.x, acc[8]);  acc[9]  = fmaf(w, sc.y, acc[9]);
        acc[10] = fmaf(w, sc.z, acc[10]); acc[11] = fmaf(w, sc.w, acc[11]);
        acc[12] = fmaf(w, sd.x, acc[12]); acc[13] = fmaf(w, sd.y, acc[13]);
        acc[14] = fmaf(w, sd.z, acc[14]); acc[15] = fmaf(w, sd.w, acc[15]);
        acc[16] = fmaf(w, se.x, acc[16]); acc[17] = fmaf(w, se.y, acc[17]);
      }
    }

    if (wave > 0) {
#pragma unroll
      for (int c = 0; c < CCH; ++c) buf[wave - 1][lane][c] = acc[c];
    }
    __syncthreads();
    if (wave == 0 && vp) {
      int myp = __float_as_int(pt.w);
      float* o = out + (size_t)myp * CCH;
#pragma unroll
      for (int c = 0; c < CCH; ++c)
        o[c] = acc[c] + buf[0][lane][c] + buf[1][lane][c] + buf[2][lane][c];
    }
    __syncthreads();
  }
}

extern "C" void kernel_launch(void* const* d_in, const int* in_sizes, int n_in,
                              void* d_out, int out_size, void* d_ws, size_t ws_size,
                              hipStream_t stream) {
  const float* pts     = (const float*)d_in[0];
  const float* means3D = (const float*)d_in[1];
  const float* opac    = (const float*)d_in[2];
  const float* sem     = (const float*)d_in[3];
  const float* scales  = (const float*)d_in[4];
  const float* cov3D   = (const float*)d_in[5];
  float* out = (float*)d_out;

  int N = in_sizes[0] / 3;
  int M = in_sizes[1] / 3;

  char* ws = (char*)d_ws;
  size_t off = 0;
  auto alloc = [&](size_t bytes) { char* p = ws + off; off = (off + bytes + 255) & ~(size_t)255; return p; };
  int*            cnt   = (int*)alloc((size_t)2 * NCELLS * 4);
  unsigned short* plist = (unsigned short*)alloc((size_t)NCELLS * PCAP * 2);
  unsigned short* glist = (unsigned short*)alloc((size_t)NCELLS * GCAP * 2);
  unsigned short* pcell = (unsigned short*)alloc((size_t)N * 2);   // fallback only
  unsigned*       gcb   = (unsigned*)alloc((size_t)M * 4);         // fallback only

  void* args[] = {(void*)&pts, (void*)&means3D, (void*)&opac, (void*)&scales,
                  (void*)&cov3D, (void*)&sem, (void*)&out, (void*)&cnt,
                  (void*)&plist, (void*)&glist, (void*)&N, (void*)&M};
  hipError_t e = hipLaunchCooperativeKernel(
      reinterpret_cast<void*>(coop_kernel), dim3(NCELLS), dim3(256), args, 0, stream);

  if (e != hipSuccess) {
    // proven R8 path: descriptor prep + scanning agg
    prep_kernel<<<(N + M + 255) / 256, 256, 0, stream>>>(
        pts, means3D, scales, pcell, gcb, N, M);
    agg_kernel<<<NCELLS, 256, 0, stream>>>(
        pts, means3D, opac, scales, cov3D, sem, pcell, gcb, out, N, M);
  }
}

// Round 10
// 27.543 us; speedup vs baseline: 7.5404x; 7.5404x over previous
//
#include <hip/hip_runtime.h>
#include <cmath>

namespace {
constexpr float GRIDSZ = 0.4f;
constexpr float PCXY = -40.0f;   // pc_min.x == pc_min.y
constexpr float PCZ  = -1.0f;
constexpr int CCH = 18;          // semantic channels
constexpr int GX = 16;           // 16x16 supercells of 13x13 voxels (208 >= 200)
constexpr int SX = 13;           // voxels per supercell side
constexpr int NSC = GX * GX;     // 256 blocks -> 1/CU, ILP hides scan latency
constexpr int PCAP = 192;        // points per supercell (mean ~64, max ~110)
constexpr int GCAP = 128;        // candidates per supercell (mean ~45, max ~80)
constexpr int SEMW = 20;         // padded semantic row in LDS (80 B)
constexpr int BLO = 5;           // B table covers k in [-5, 218]
constexpr int BN  = 224;

struct BTab {
  float B[BN];          // B[k+BLO] = min float x with floorf((x-PCXY)/GRIDSZ) >= k
  float T2, T3, T4;     // max float s with (s*3f)/GRIDSZ <= k, k=2,3,4
};

// Host: exact f32 boundary search (host and device are both IEEE binary32 RN,
// identical ops -> identical results). Verified correct in R7's passing run.
void build_btab(BTab& bt) {
  auto f = [](float x) { return floorf((x - PCXY) / GRIDSZ); };
  for (int i = 0; i < BN; ++i) {
    int k = i - BLO;
    float fk = (float)k;
    float x = (float)(-40.0 + 0.4 * (double)k);
    int guard = 0;
    while (f(x) >= fk && guard++ < 4096) x = nextafterf(x, -3.0e38f);
    guard = 0;
    while (f(x) < fk && guard++ < 4096) x = nextafterf(x, 3.0e38f);
    bt.B[i] = x;
  }
  auto v = [](float s) { return (s * 3.0f) / GRIDSZ; };
  float tk[3];
  for (int k = 2; k <= 4; ++k) {
    float fk = (float)k;
    float s = (float)(0.4 * (double)k / 3.0);
    int guard = 0;
    while (v(s) <= fk && guard++ < 4096) s = nextafterf(s, 3.0e38f);
    guard = 0;
    while (v(s) > fk && guard++ < 4096) s = nextafterf(s, -3.0e38f);
    tk[k - 2] = s;
  }
  bt.T2 = tk[0]; bt.T3 = tk[1]; bt.T4 = tk[2];
}
} // namespace

// ONE kernel, one block per 13x13-voxel supercell. Scan = raw-float interval
// compares against exact precomputed boundaries (zero divisions). Survivors
// (~64 pts, ~45 gaussians) get exact IEEE voxelization + payloads; the dense
// point x candidate loop runs entirely from LDS. Deterministic: candidates
// rank-sorted; fixed wave-quarter split and cross-wave sum order.
__global__ __launch_bounds__(256) void fused_kernel(
    const float* __restrict__ pts, const float* __restrict__ means,
    const float* __restrict__ opac, const float* __restrict__ scales,
    const float* __restrict__ cov, const float* __restrict__ sem,
    float* __restrict__ out, int N, int M, BTab bt) {
  __shared__ int pcnt_s, gcnt_s;
  __shared__ int lpi[PCAP];
  __shared__ int lvox[PCAP];
  __shared__ float4 lpts[PCAP];
  __shared__ int graw[GCAP];
  __shared__ int gsrt[GCAP];
  __shared__ int4 lbox[GCAP];
  __shared__ float4 lpay[GCAP * 3];
  __shared__ float lsem[GCAP * SEMW];
  __shared__ float buf[3][64][CCH + 1];  // +1 pad -> 19-word lane stride

  const int tid = threadIdx.x, lane = tid & 63, wave = tid >> 6;
  const int qx = blockIdx.x & (GX - 1), qy = blockIdx.x >> 4;

  // Exact interval bounds for this supercell (uniform -> SGPRs).
  const int ix0 = SX * qx + BLO, iy0 = SX * qy + BLO;
  const float pxlo = bt.B[ix0],      pxhi = bt.B[ix0 + SX];
  const float pylo = bt.B[iy0],      pyhi = bt.B[iy0 + SX];
  const float gxl2 = bt.B[ix0 - 2], gxl3 = bt.B[ix0 - 3], gxl4 = bt.B[ix0 - 4], gxl5 = bt.B[ix0 - 5];
  const float gxh2 = bt.B[ix0 + SX + 2], gxh3 = bt.B[ix0 + SX + 3], gxh4 = bt.B[ix0 + SX + 4], gxh5 = bt.B[ix0 + SX + 5];
  const float gyl2 = bt.B[iy0 - 2], gyl3 = bt.B[iy0 - 3], gyl4 = bt.B[iy0 - 4], gyl5 = bt.B[iy0 - 5];
  const float gyh2 = bt.B[iy0 + SX + 2], gyh3 = bt.B[iy0 + SX + 3], gyh4 = bt.B[iy0 + SX + 4], gyh5 = bt.B[iy0 + SX + 5];

  if (tid == 0) { pcnt_s = 0; gcnt_s = 0; }
  __syncthreads();

  // Phase A: point scan — 4 points per 3 float4 loads, interval compares only.
  {
    const float4* p4 = reinterpret_cast<const float4*>(pts);
    const int ng = N >> 2;
    for (int gq = tid; gq < ng; gq += 256) {
      float4 v0 = p4[gq * 3 + 0], v1 = p4[gq * 3 + 1], v2 = p4[gq * 3 + 2];
      float ax[4] = {v0.x, v0.w, v1.z, v2.y};
      float ay[4] = {v0.y, v1.x, v1.w, v2.z};
#pragma unroll
      for (int k = 0; k < 4; ++k) {
        if (ax[k] >= pxlo && ax[k] < pxhi && ay[k] >= pylo && ay[k] < pyhi) {
          int s = atomicAdd(&pcnt_s, 1);
          if (s < PCAP) lpi[s] = gq * 4 + k;
        }
      }
    }
    for (int i = (ng << 2) + tid; i < N; i += 256) {  // tail (none for N=16384)
      float px = pts[(size_t)i * 3], py = pts[(size_t)i * 3 + 1];
      if (px >= pxlo && px < pxhi && py >= pylo && py < pyhi) {
        int s = atomicAdd(&pcnt_s, 1);
        if (s < PCAP) lpi[s] = i;
      }
    }
  }
  // Phase B: gaussian scan — radius class via exact thresholds, interval test.
  {
    const float4* m4 = reinterpret_cast<const float4*>(means);
    const float4* s4 = reinterpret_cast<const float4*>(scales);
    const int mg = M >> 2;
    for (int gq = tid; gq < mg; gq += 256) {
      float4 a0 = m4[gq * 3 + 0], a1 = m4[gq * 3 + 1], a2 = m4[gq * 3 + 2];
      float4 b0 = s4[gq * 3 + 0], b1 = s4[gq * 3 + 1], b2 = s4[gq * 3 + 2];
      float ax[4] = {a0.x, a0.w, a1.z, a2.y};
      float ay[4] = {a0.y, a1.x, a1.w, a2.z};
      float sm[4] = {fmaxf(b0.x, fmaxf(b0.y, b0.z)), fmaxf(b0.w, fmaxf(b1.x, b1.y)),
                     fmaxf(b1.z, fmaxf(b1.w, b2.x)), fmaxf(b2.y, fmaxf(b2.z, b2.w))};
#pragma unroll
      for (int k = 0; k < 4; ++k) {
        int ri = (sm[k] > bt.T2) + (sm[k] > bt.T3) + (sm[k] > bt.T4);  // r = ri+2
        float xl = (ri == 0) ? gxl2 : (ri == 1) ? gxl3 : (ri == 2) ? gxl4 : gxl5;
        float xh = (ri == 0) ? gxh2 : (ri == 1) ? gxh3 : (ri == 2) ? gxh4 : gxh5;
        float yl = (ri == 0) ? gyl2 : (ri == 1) ? gyl3 : (ri == 2) ? gyl4 : gyl5;
        float yh = (ri == 0) ? gyh2 : (ri == 1) ? gyh3 : (ri == 2) ? gyh4 : gyh5;
        if (ax[k] >= xl && ax[k] < xh && ay[k] >= yl && ay[k] < yh) {
          int s = atomicAdd(&gcnt_s, 1);
          if (s < GCAP) graw[s] = gq * 4 + k;
        }
      }
    }
    for (int g = (mg << 2) + tid; g < M; g += 256) {  // tail (none for M=4096)
      float mx = means[(size_t)g * 3], my = means[(size_t)g * 3 + 1];
      float sm = fmaxf(scales[(size_t)g * 3],
                 fmaxf(scales[(size_t)g * 3 + 1], scales[(size_t)g * 3 + 2]));
      int ri = (sm > bt.T2) + (sm > bt.T3) + (sm > bt.T4);
      float xl = (ri == 0) ? gxl2 : (ri == 1) ? gxl3 : (ri == 2) ? gxl4 : gxl5;
      float xh = (ri == 0) ? gxh2 : (ri == 1) ? gxh3 : (ri == 2) ? gxh4 : gxh5;
      float yl = (ri == 0) ? gyl2 : (ri == 1) ? gyl3 : (ri == 2) ? gyl4 : gyl5;
      float yh = (ri == 0) ? gyh2 : (ri == 1) ? gyh3 : (ri == 2) ? gyh4 : gyh5;
      if (mx >= xl && mx < xh && my >= yl && my < yh) {
        int s = atomicAdd(&gcnt_s, 1);
        if (s < GCAP) graw[s] = g;
      }
    }
  }
  __syncthreads();
  const int P = min(pcnt_s, PCAP);
  const int K = min(gcnt_s, GCAP);

  // rank-sort candidates ascending: deterministic accumulation order
  if (tid < K) {
    int v = graw[tid], rank = 0;
    for (int j = 0; j < K; ++j) rank += (graw[j] < v);
    gsrt[rank] = v;
  }
  __syncthreads();

  // Phase C: survivors only — exact IEEE voxelization + payload build.
  for (int t = tid; t < P; t += 256) {
    int i = lpi[t];
    float px = pts[(size_t)i * 3], py = pts[(size_t)i * 3 + 1], pz = pts[(size_t)i * 3 + 2];
    int pvx = (int)floorf((px - PCXY) / GRIDSZ);
    int pvy = (int)floorf((py - PCXY) / GRIDSZ);
    int pvz = (int)floorf((pz - PCZ) / GRIDSZ);
    lvox[t] = pvx | (pvy << 8) | (pvz << 16);
    lpts[t] = make_float4(px, py, pz, __int_as_float(i));
  }
  for (int t = tid; t < K; t += 256) {
    int g = gsrt[t];
    float mx = means[(size_t)g * 3], my = means[(size_t)g * 3 + 1], mz = means[(size_t)g * 3 + 2];
    int mvx = (int)floorf((mx - PCXY) / GRIDSZ);
    int mvy = (int)floorf((my - PCXY) / GRIDSZ);
    int mvz = (int)floorf((mz - PCZ) / GRIDSZ);
    float sm = fmaxf(scales[(size_t)g * 3],
               fmaxf(scales[(size_t)g * 3 + 1], scales[(size_t)g * 3 + 2]));
    int r = (int)ceilf(sm * 3.0f / GRIDSZ);
    lbox[t] = make_int4(mvx - r, mvy - r, mvz - r, 2 * r);
    const float* c = cov + (size_t)g * 9;
    float c00 = c[0], c01 = c[1], c02 = c[2], c11 = c[4], c12 = c[5], c22 = c[8];
    float M00 = c11 * c22 - c12 * c12;
    float M01 = c02 * c12 - c01 * c22;
    float M02 = c01 * c12 - c02 * c11;
    float inv = 1.0f / (c00 * M00 + c01 * M01 + c02 * M02);
    lpay[t * 3 + 0] = make_float4(mx, my, mz, opac[g]);
    lpay[t * 3 + 1] = make_float4(M00 * inv, M01 * inv, M02 * inv,
                                  (c00 * c22 - c02 * c02) * inv);
    lpay[t * 3 + 2] = make_float4((c01 * c02 - c00 * c12) * inv,
                                  (c00 * c11 - c01 * c01) * inv, 0.f, 0.f);
  }
  for (int idx = tid; idx < K * CCH; idx += 256) {
    int j = idx / CCH, c2 = idx - j * CCH;
    lsem[j * SEMW + c2] = sem[(size_t)gsrt[j] * CCH + c2];
  }
  __syncthreads();

  // Phase D: dense point x candidate loop, wave-quartered (deterministic).
  const int kq = (K + 3) >> 2;
  const int j0 = wave * kq, j1 = min(K, j0 + kq);

  for (int pb = 0; pb < P; pb += 64) {
    const bool vp = (pb + lane) < P;
    const float4 pt = lpts[vp ? pb + lane : 0];
    const int pv = vp ? lvox[pb + lane] : 0;
    int pvx = vp ? (pv & 255) : -100000;  // sentinel fails every box
    int pvy = (pv >> 8) & 255;
    int pvz = pv >> 16;

    float acc[CCH];
#pragma unroll
    for (int c = 0; c < CCH; ++c) acc[c] = 0.f;

    for (int j = j0; j < j1; ++j) {
      int4 bx = lbox[j];  // uniform -> LDS broadcast
      bool m = ((unsigned)(pvx - bx.x) <= (unsigned)bx.w) &
               ((unsigned)(pvy - bx.y) <= (unsigned)bx.w) &
               ((unsigned)(pvz - bx.z) <= (unsigned)bx.w);
      if (__any(m)) {
        float4 q0 = lpay[j * 3 + 0];
        float4 q1 = lpay[j * 3 + 1];
        float4 q2 = lpay[j * 3 + 2];
        float dx = pt.x - q0.x, dy = pt.y - q0.y, dz = pt.z - q0.z;
        float t0 = q1.x * dx + q1.y * dy + q1.z * dz;
        float t1 = q1.y * dx + q1.w * dy + q2.x * dz;
        float t2 = q1.z * dx + q2.x * dy + q2.y * dz;
        float qq = dx * t0 + dy * t1 + dz * t2;
        float w = m ? __expf(-0.5f * qq) * q0.w : 0.f;
        const float4* s4 = reinterpret_cast<const float4*>(&lsem[j * SEMW]);
        float4 sa = s4[0], sb = s4[1], sc = s4[2], sd = s4[3];
        float2 se = *reinterpret_cast<const float2*>(&lsem[j * SEMW + 16]);
        acc[0]  = fmaf(w, sa.x, acc[0]);  acc[1]  = fmaf(w, sa.y, acc[1]);
        acc[2]  = fmaf(w, sa.z, acc[2]);  acc[3]  = fmaf(w, sa.w, acc[3]);
        acc[4]  = fmaf(w, sb.x, acc[4]);  acc[5]  = fmaf(w, sb.y, acc[5]);
        acc[6]  = fmaf(w, sb.z, acc[6]);  acc[7]  = fmaf(w, sb.w, acc[7]);
        acc[8]  = fmaf(w, sc.x, acc[8]);  acc[9]  = fmaf(w, sc.y, acc[9]);
        acc[10] = fmaf(w, sc.z, acc[10]); acc[11] = fmaf(w, sc.w, acc[11]);
        acc[12] = fmaf(w, sd.x, acc[12]); acc[13] = fmaf(w, sd.y, acc[13]);
        acc[14] = fmaf(w, sd.z, acc[14]); acc[15] = fmaf(w, sd.w, acc[15]);
        acc[16] = fmaf(w, se.x, acc[16]); acc[17] = fmaf(w, se.y, acc[17]);
      }
    }

    // deterministic cross-wave reduce, one write per point
    if (wave > 0) {
#pragma unroll
      for (int c = 0; c < CCH; ++c) buf[wave - 1][lane][c] = acc[c];
    }
    __syncthreads();
    if (wave == 0 && vp) {
      int myp = __float_as_int(pt.w);
      float* o = out + (size_t)myp * CCH;
#pragma unroll
      for (int c = 0; c < CCH; ++c)
        o[c] = acc[c] + buf[0][lane][c] + buf[1][lane][c] + buf[2][lane][c];
    }
    __syncthreads();  // buf reused by next point-chunk
  }
}

extern "C" void kernel_launch(void* const* d_in, const int* in_sizes, int n_in,
                              void* d_out, int out_size, void* d_ws, size_t ws_size,
                              hipStream_t stream) {
  const float* pts     = (const float*)d_in[0];
  const float* means3D = (const float*)d_in[1];
  const float* opac    = (const float*)d_in[2];
  const float* sem     = (const float*)d_in[3];
  const float* scales  = (const float*)d_in[4];
  const float* cov3D   = (const float*)d_in[5];
  float* out = (float*)d_out;

  int N = in_sizes[0] / 3;
  int M = in_sizes[1] / 3;

  BTab bt;
  build_btab(bt);  // deterministic, input-independent; baked into the graph

  fused_kernel<<<NSC, 256, 0, stream>>>(
      pts, means3D, opac, scales, cov3D, sem, out, N, M, bt);
}

// Round 11
// 27.185 us; speedup vs baseline: 7.6395x; 1.0131x over previous
//
#include <hip/hip_runtime.h>

namespace {
constexpr float GRIDSZ = 0.4f;
constexpr float PCXY = -40.0f;   // pc_min.x == pc_min.y
constexpr float PCZ  = -1.0f;
constexpr int CCH = 18;          // semantic channels
constexpr int CELLS_X = 25;      // 200 voxels / 8 per xy-cell (z not binned)
constexpr int NCELLS = CELLS_X * CELLS_X;  // 625
constexpr int VMAX = 199;        // max voxel index in x,y
constexpr int BCELL = 2;         // cells per agg block (scan amortization)
constexpr int NBLK = (NCELLS + BCELL - 1) / BCELL;  // 313
constexpr int PCAP = 128;        // per-cell point cap (mean ~26)
constexpr int GCAP = 128;        // per-cell candidate cap (mean ~28)
constexpr int SEMW = 20;         // padded semantic row in LDS (80 B)
}

// Pass 1: descriptors only. 2 B/point (cell id), 2 B/gaussian (packed cellbox:
// cx0[5] | dx[2] | cy0[5] | dy[2]; dx,dy <= 2 since box span <= 11 voxels).
// All survivor data is recomputed in agg with identical IEEE f32 ops.
__global__ __launch_bounds__(256) void prep_kernel(
    const float* __restrict__ pts, const float* __restrict__ means,
    const float* __restrict__ scales,
    unsigned short* __restrict__ pcell, unsigned short* __restrict__ gcb,
    int N, int M) {
  int id = blockIdx.x * 256 + threadIdx.x;
  if (id < M) {
    int g = id;
    float mx = means[(size_t)g * 3 + 0], my = means[(size_t)g * 3 + 1];
    // must match numpy floor((x-pc_min)/GRID) in f32 exactly
    int mvx = (int)floorf((mx - PCXY) / GRIDSZ);
    int mvy = (int)floorf((my - PCXY) / GRIDSZ);
    float smax = fmaxf(scales[(size_t)g * 3 + 0],
                 fmaxf(scales[(size_t)g * 3 + 1], scales[(size_t)g * 3 + 2]));
    int r = (int)ceilf(smax * 3.0f / GRIDSZ);
    int cx0 = max(mvx - r, 0) >> 3, cx1 = min(mvx + r, VMAX) >> 3;
    int cy0 = max(mvy - r, 0) >> 3, cy1 = min(mvy + r, VMAX) >> 3;
    gcb[g] = (unsigned short)((unsigned)cx0 | ((unsigned)(cx1 - cx0) << 5) |
                              ((unsigned)cy0 << 7) | ((unsigned)(cy1 - cy0) << 12));
  } else if (id < M + N) {
    int p = id - M;
    float px = pts[(size_t)p * 3 + 0], py = pts[(size_t)p * 3 + 1];
    int pvx = (int)floorf((px - PCXY) / GRIDSZ);
    int pvy = (int)floorf((py - PCXY) / GRIDSZ);
    pcell[p] = (unsigned short)((pvx >> 3) + CELLS_X * (pvy >> 3));
  }
}

// Pass 2: one block per 2 consecutive cells. Single 40 KB descriptor scan
// fills both cells' index lists; phases C/D run per cell from a shared LDS
// working set. Deterministic: candidates rank-sorted; fixed wave-quarter
// split and cross-wave sum order; one writer per point.
__global__ __launch_bounds__(256) void agg_kernel(
    const float* __restrict__ pts, const float* __restrict__ means,
    const float* __restrict__ opac, const float* __restrict__ scales,
    const float* __restrict__ cov, const float* __restrict__ sem,
    const unsigned short* __restrict__ pcell, const unsigned short* __restrict__ gcb,
    float* __restrict__ out, int N, int M) {
  __shared__ int pcnt_s[BCELL], gcnt_s[BCELL];
  __shared__ int lpi2[BCELL][PCAP];
  __shared__ int graw2[BCELL][GCAP];
  __shared__ int gsrt[GCAP];
  __shared__ int lvox[PCAP];
  __shared__ float4 lpts[PCAP];
  __shared__ int4 lbox[GCAP];
  __shared__ float4 lpay[GCAP * 3];
  __shared__ float lsem[GCAP * SEMW];
  __shared__ float buf[3][64][CCH + 1];  // +1 pad -> 19-word lane stride

  const int tid = threadIdx.x, lane = tid & 63, wave = tid >> 6;
  const unsigned c0 = blockIdx.x * BCELL;
  const int cxA = (int)(c0 % CELLS_X), cyA = (int)(c0 / CELLS_X);
  const bool has1 = (c0 + 1) < NCELLS;
  const int cxB = has1 ? (int)((c0 + 1) % CELLS_X) : 255;
  const int cyB = has1 ? (int)((c0 + 1) / CELLS_X) : 255;

  if (tid < BCELL) { pcnt_s[tid] = 0; gcnt_s[tid] = 0; }
  __syncthreads();

  // Phase A: point scan — 8 ushort cell-ids per uint4; consecutive-cell test.
  {
    const uint4* pc4 = reinterpret_cast<const uint4*>(pcell);
    const int n8 = N >> 3;
    for (int i8 = tid; i8 < n8; i8 += 256) {
      uint4 v = pc4[i8];
      unsigned w[4] = {v.x, v.y, v.z, v.w};
#pragma unroll
      for (int k = 0; k < 4; ++k) {
        unsigned dlo = (w[k] & 0xFFFFu) - c0;
        if (dlo < (unsigned)BCELL) {
          int s = atomicAdd(&pcnt_s[dlo], 1);
          if (s < PCAP) lpi2[dlo][s] = i8 * 8 + 2 * k;
        }
        unsigned dhi = (w[k] >> 16) - c0;
        if (dhi < (unsigned)BCELL) {
          int s = atomicAdd(&pcnt_s[dhi], 1);
          if (s < PCAP) lpi2[dhi][s] = i8 * 8 + 2 * k + 1;
        }
      }
    }
    for (int i = (n8 << 3) + tid; i < N; i += 256) {  // tail (none for N=16384)
      unsigned d = (unsigned)pcell[i] - c0;
      if (d < (unsigned)BCELL) {
        int s = atomicAdd(&pcnt_s[d], 1);
        if (s < PCAP) lpi2[d][s] = i;
      }
    }
  }
  // Phase B: gaussian scan — 8 packed cellboxes per uint4, test vs both cells.
  {
    const uint4* gb4 = reinterpret_cast<const uint4*>(gcb);
    const int m8 = M >> 3;
    for (int i8 = tid; i8 < m8; i8 += 256) {
      uint4 v = gb4[i8];
      unsigned w[4] = {v.x, v.y, v.z, v.w};
#pragma unroll
      for (int k = 0; k < 4; ++k) {
#pragma unroll
        for (int h = 0; h < 2; ++h) {
          unsigned u = (h == 0) ? (w[k] & 0xFFFFu) : (w[k] >> 16);
          int g = i8 * 8 + 2 * k + h;
          int gx0 = (int)(u & 31u), dx = (int)((u >> 5) & 3u);
          int gy0 = (int)((u >> 7) & 31u), dy = (int)((u >> 12) & 3u);
          if (((unsigned)(cxA - gx0) <= (unsigned)dx) &
              ((unsigned)(cyA - gy0) <= (unsigned)dy)) {
            int s = atomicAdd(&gcnt_s[0], 1);
            if (s < GCAP) graw2[0][s] = g;
          }
          if (((unsigned)(cxB - gx0) <= (unsigned)dx) &
              ((unsigned)(cyB - gy0) <= (unsigned)dy)) {
            int s = atomicAdd(&gcnt_s[1], 1);
            if (s < GCAP) graw2[1][s] = g;
          }
        }
      }
    }
    for (int g = (m8 << 3) + tid; g < M; g += 256) {  // tail (none for M=4096)
      unsigned u = gcb[g];
      int gx0 = (int)(u & 31u), dx = (int)((u >> 5) & 3u);
      int gy0 = (int)((u >> 7) & 31u), dy = (int)((u >> 12) & 3u);
      if (((unsigned)(cxA - gx0) <= (unsigned)dx) & ((unsigned)(cyA - gy0) <= (unsigned)dy)) {
        int s = atomicAdd(&gcnt_s[0], 1);
        if (s < GCAP) graw2[0][s] = g;
      }
      if (((unsigned)(cxB - gx0) <= (unsigned)dx) & ((unsigned)(cyB - gy0) <= (unsigned)dy)) {
        int s = atomicAdd(&gcnt_s[1], 1);
        if (s < GCAP) graw2[1][s] = g;
      }
    }
  }
  __syncthreads();

  const int ncc = has1 ? BCELL : 1;
  for (int cc = 0; cc < ncc; ++cc) {
    const int P = min(pcnt_s[cc], PCAP);
    const int K = min(gcnt_s[cc], GCAP);

    // rank-sort candidates ascending: deterministic accumulation order
    if (tid < K) {
      int v = graw2[cc][tid], rank = 0;
      for (int j = 0; j < K; ++j) rank += (graw2[cc][j] < v);
      gsrt[rank] = v;
    }
    __syncthreads();

    // Phase C: survivors only — exact IEEE voxelization + payload build.
    if (tid < P) {
      int i = lpi2[cc][tid];
      float px = pts[(size_t)i * 3], py = pts[(size_t)i * 3 + 1], pz = pts[(size_t)i * 3 + 2];
      int pvx = (int)floorf((px - PCXY) / GRIDSZ);
      int pvy = (int)floorf((py - PCXY) / GRIDSZ);
      int pvz = (int)floorf((pz - PCZ) / GRIDSZ);
      lvox[tid] = pvx | (pvy << 8) | (pvz << 16);
      lpts[tid] = make_float4(px, py, pz, __int_as_float(i));
    } else if (tid >= 128 && tid - 128 < K) {
      int t = tid - 128;
      int g = gsrt[t];
      float mx = means[(size_t)g * 3], my = means[(size_t)g * 3 + 1], mz = means[(size_t)g * 3 + 2];
      int mvx = (int)floorf((mx - PCXY) / GRIDSZ);
      int mvy = (int)floorf((my - PCXY) / GRIDSZ);
      int mvz = (int)floorf((mz - PCZ) / GRIDSZ);
      float sm = fmaxf(scales[(size_t)g * 3],
                 fmaxf(scales[(size_t)g * 3 + 1], scales[(size_t)g * 3 + 2]));
      int r = (int)ceilf(sm * 3.0f / GRIDSZ);
      lbox[t] = make_int4(mvx - r, mvy - r, mvz - r, 2 * r);
      const float* c = cov + (size_t)g * 9;
      float c00 = c[0], c01 = c[1], c02 = c[2], c11 = c[4], c12 = c[5], c22 = c[8];
      float M00 = c11 * c22 - c12 * c12;
      float M01 = c02 * c12 - c01 * c22;
      float M02 = c01 * c12 - c02 * c11;
      float inv = 1.0f / (c00 * M00 + c01 * M01 + c02 * M02);
      lpay[t * 3 + 0] = make_float4(mx, my, mz, opac[g]);
      lpay[t * 3 + 1] = make_float4(M00 * inv, M01 * inv, M02 * inv,
                                    (c00 * c22 - c02 * c02) * inv);
      lpay[t * 3 + 2] = make_float4((c01 * c02 - c00 * c12) * inv,
                                    (c00 * c11 - c01 * c01) * inv, 0.f, 0.f);
    }
    for (int idx = tid; idx < K * CCH; idx += 256) {
      int j = idx / CCH, c2 = idx - j * CCH;
      lsem[j * SEMW + c2] = sem[(size_t)gsrt[j] * CCH + c2];
    }
    __syncthreads();

    // Phase D: dense point x candidate loop, wave-quartered.
    const int kq = (K + 3) >> 2;
    const int j0 = wave * kq, j1 = min(K, j0 + kq);

    for (int pb = 0; pb < P; pb += 64) {
      const bool vp = (pb + lane) < P;
      const float4 pt = lpts[vp ? pb + lane : 0];
      const int pv = vp ? lvox[pb + lane] : 0;
      int pvx = vp ? (pv & 255) : -100000;  // sentinel fails every box
      int pvy = (pv >> 8) & 255;
      int pvz = pv >> 16;

      float acc[CCH];
#pragma unroll
      for (int c = 0; c < CCH; ++c) acc[c] = 0.f;

      for (int j = j0; j < j1; ++j) {
        int4 bx = lbox[j];  // uniform -> LDS broadcast
        bool m = ((unsigned)(pvx - bx.x) <= (unsigned)bx.w) &
                 ((unsigned)(pvy - bx.y) <= (unsigned)bx.w) &
                 ((unsigned)(pvz - bx.z) <= (unsigned)bx.w);
        if (__any(m)) {
          float4 q0 = lpay[j * 3 + 0];
          float4 q1 = lpay[j * 3 + 1];
          float4 q2 = lpay[j * 3 + 2];
          float dx = pt.x - q0.x, dy = pt.y - q0.y, dz = pt.z - q0.z;
          float t0 = q1.x * dx + q1.y * dy + q1.z * dz;
          float t1 = q1.y * dx + q1.w * dy + q2.x * dz;
          float t2 = q1.z * dx + q2.x * dy + q2.y * dz;
          float qq = dx * t0 + dy * t1 + dz * t2;
          float w = m ? __expf(-0.5f * qq) * q0.w : 0.f;
          const float4* s4 = reinterpret_cast<const float4*>(&lsem[j * SEMW]);
          float4 sa = s4[0], sb = s4[1], sc = s4[2], sd = s4[3];
          float2 se = *reinterpret_cast<const float2*>(&lsem[j * SEMW + 16]);
          acc[0]  = fmaf(w, sa.x, acc[0]);  acc[1]  = fmaf(w, sa.y, acc[1]);
          acc[2]  = fmaf(w, sa.z, acc[2]);  acc[3]  = fmaf(w, sa.w, acc[3]);
          acc[4]  = fmaf(w, sb.x, acc[4]);  acc[5]  = fmaf(w, sb.y, acc[5]);
          acc[6]  = fmaf(w, sb.z, acc[6]);  acc[7]  = fmaf(w, sb.w, acc[7]);
          acc[8]  = fmaf(w, sc.x, acc[8]);  acc[9]  = fmaf(w, sc.y, acc[9]);
          acc[10] = fmaf(w, sc.z, acc[10]); acc[11] = fmaf(w, sc.w, acc[11]);
          acc[12] = fmaf(w, sd.x, acc[12]); acc[13] = fmaf(w, sd.y, acc[13]);
          acc[14] = fmaf(w, sd.z, acc[14]); acc[15] = fmaf(w, sd.w, acc[15]);
          acc[16] = fmaf(w, se.x, acc[16]); acc[17] = fmaf(w, se.y, acc[17]);
        }
      }

      // deterministic cross-wave reduce, one write per point
      if (wave > 0) {
#pragma unroll
        for (int c = 0; c < CCH; ++c) buf[wave - 1][lane][c] = acc[c];
      }
      __syncthreads();
      if (wave == 0 && vp) {
        int myp = __float_as_int(pt.w);
        float* o = out + (size_t)myp * CCH;
#pragma unroll
        for (int c = 0; c < CCH; ++c)
          o[c] = acc[c] + buf[0][lane][c] + buf[1][lane][c] + buf[2][lane][c];
      }
      __syncthreads();  // buf + working set reused by next chunk / next cell
    }
  }
}

extern "C" void kernel_launch(void* const* d_in, const int* in_sizes, int n_in,
                              void* d_out, int out_size, void* d_ws, size_t ws_size,
                              hipStream_t stream) {
  const float* pts     = (const float*)d_in[0];
  const float* means3D = (const float*)d_in[1];
  const float* opac    = (const float*)d_in[2];
  const float* sem     = (const float*)d_in[3];
  const float* scales  = (const float*)d_in[4];
  const float* cov3D   = (const float*)d_in[5];
  float* out = (float*)d_out;

  int N = in_sizes[0] / 3;
  int M = in_sizes[1] / 3;

  char* ws = (char*)d_ws;
  size_t off = 0;
  auto alloc = [&](size_t bytes) { char* p = ws + off; off = (off + bytes + 255) & ~(size_t)255; return p; };
  unsigned short* pcell = (unsigned short*)alloc((size_t)N * 2);
  unsigned short* gcb   = (unsigned short*)alloc((size_t)M * 2);

  prep_kernel<<<(N + M + 255) / 256, 256, 0, stream>>>(
      pts, means3D, scales, pcell, gcb, N, M);

  agg_kernel<<<NBLK, 256, 0, stream>>>(
      pts, means3D, opac, scales, cov3D, sem, pcell, gcb, out, N, M);
}

// Round 12
// 21.655 us; speedup vs baseline: 9.5903x; 1.2554x over previous
//
#include <hip/hip_runtime.h>

namespace {
constexpr float GRIDSZ = 0.4f;
constexpr float PCXY = -40.0f;   // pc_min.x == pc_min.y
constexpr float PCZ  = -1.0f;
constexpr int CCH = 18;          // semantic channels
constexpr int CELLS_X = 25;      // 200 voxels / 8 per xy-cell (z not binned)
constexpr int NCELLS = CELLS_X * CELLS_X;  // 625 blocks: best measured (latency-bound scan)
constexpr int VMAX = 199;        // max voxel index in x,y
constexpr int PCAP = 128;        // per-cell point cap (mean ~26)
constexpr int GCAP = 128;        // per-cell candidate cap (mean ~28)
constexpr int SEMW = 20;         // padded semantic row in LDS (80 B)
}

// Pass 1: descriptors only. 2 B/point (cell id), 2 B/gaussian (packed cellbox:
// cx0[5] | dx[2] | cy0[5] | dy[2]; dx,dy <= 2 since box span <= 11 voxels).
// All survivor data is recomputed in agg with identical IEEE f32 ops.
__global__ __launch_bounds__(256) void prep_kernel(
    const float* __restrict__ pts, const float* __restrict__ means,
    const float* __restrict__ scales,
    unsigned short* __restrict__ pcell, unsigned short* __restrict__ gcb,
    int N, int M) {
  int id = blockIdx.x * 256 + threadIdx.x;
  if (id < M) {
    int g = id;
    float mx = means[(size_t)g * 3 + 0], my = means[(size_t)g * 3 + 1];
    // must match numpy floor((x-pc_min)/GRID) in f32 exactly
    int mvx = (int)floorf((mx - PCXY) / GRIDSZ);
    int mvy = (int)floorf((my - PCXY) / GRIDSZ);
    float smax = fmaxf(scales[(size_t)g * 3 + 0],
                 fmaxf(scales[(size_t)g * 3 + 1], scales[(size_t)g * 3 + 2]));
    int r = (int)ceilf(smax * 3.0f / GRIDSZ);
    int cx0 = max(mvx - r, 0) >> 3, cx1 = min(mvx + r, VMAX) >> 3;
    int cy0 = max(mvy - r, 0) >> 3, cy1 = min(mvy + r, VMAX) >> 3;
    gcb[g] = (unsigned short)((unsigned)cx0 | ((unsigned)(cx1 - cx0) << 5) |
                              ((unsigned)cy0 << 7) | ((unsigned)(cy1 - cy0) << 12));
  } else if (id < M + N) {
    int p = id - M;
    float px = pts[(size_t)p * 3 + 0], py = pts[(size_t)p * 3 + 1];
    int pvx = (int)floorf((px - PCXY) / GRIDSZ);
    int pvy = (int)floorf((py - PCXY) / GRIDSZ);
    pcell[p] = (unsigned short)((pvx >> 3) + CELLS_X * (pvy >> 3));
  }
}

// Pass 2 (R8 structure, proven fastest): one block per cell. Scan = 40 KB of
// packed descriptors (uint4 loads, integer compares). Survivors (~26 pts,
// ~28 gaussians) get exact IEEE voxelization + payloads in LDS; dense
// point x candidate loop runs from LDS. Deterministic: candidates rank-sorted,
// fixed wave-quarter split and cross-wave sum order, one writer per point.
__global__ __launch_bounds__(256) void agg_kernel(
    const float* __restrict__ pts, const float* __restrict__ means,
    const float* __restrict__ opac, const float* __restrict__ scales,
    const float* __restrict__ cov, const float* __restrict__ sem,
    const unsigned short* __restrict__ pcell, const unsigned short* __restrict__ gcb,
    float* __restrict__ out, int N, int M) {
  __shared__ int pcnt_s, gcnt_s;
  __shared__ int lpi[PCAP];
  __shared__ int lvox[PCAP];
  __shared__ float4 lpts[PCAP];
  __shared__ int graw[GCAP];
  __shared__ int gsrt[GCAP];
  __shared__ int4 lbox[GCAP];
  __shared__ float4 lpay[GCAP * 3];
  __shared__ float lsem[GCAP * SEMW];
  __shared__ float buf[3][64][CCH + 1];  // +1 pad -> 19-word lane stride

  const int tid = threadIdx.x, lane = tid & 63, wave = tid >> 6;
  const unsigned cellv = blockIdx.x;
  const int cx = (int)(cellv % CELLS_X), cy = (int)(cellv / CELLS_X);

  if (tid == 0) { pcnt_s = 0; gcnt_s = 0; }
  __syncthreads();

  // Phase A: point scan — 8 ushort cell-ids per uint4 load.
  {
    const uint4* pc4 = reinterpret_cast<const uint4*>(pcell);
    const int n8 = N >> 3;
    for (int i8 = tid; i8 < n8; i8 += 256) {
      uint4 v = pc4[i8];
      unsigned w[4] = {v.x, v.y, v.z, v.w};
#pragma unroll
      for (int k = 0; k < 4; ++k) {
        if ((w[k] & 0xFFFFu) == cellv) {
          int s = atomicAdd(&pcnt_s, 1);
          if (s < PCAP) lpi[s] = i8 * 8 + 2 * k;
        }
        if ((w[k] >> 16) == cellv) {
          int s = atomicAdd(&pcnt_s, 1);
          if (s < PCAP) lpi[s] = i8 * 8 + 2 * k + 1;
        }
      }
    }
    for (int i = (n8 << 3) + tid; i < N; i += 256) {  // tail (none for N=16384)
      if (pcell[i] == cellv) {
        int s = atomicAdd(&pcnt_s, 1);
        if (s < PCAP) lpi[s] = i;
      }
    }
  }
  // Phase B: gaussian scan — 8 packed cellboxes per uint4 load.
  {
    const uint4* gb4 = reinterpret_cast<const uint4*>(gcb);
    const int m8 = M >> 3;
    for (int i8 = tid; i8 < m8; i8 += 256) {
      uint4 v = gb4[i8];
      unsigned w[4] = {v.x, v.y, v.z, v.w};
#pragma unroll
      for (int k = 0; k < 4; ++k) {
#pragma unroll
        for (int h = 0; h < 2; ++h) {
          unsigned u = (h == 0) ? (w[k] & 0xFFFFu) : (w[k] >> 16);
          int gx0 = (int)(u & 31u), dx = (int)((u >> 5) & 3u);
          int gy0 = (int)((u >> 7) & 31u), dy = (int)((u >> 12) & 3u);
          if (((unsigned)(cx - gx0) <= (unsigned)dx) &
              ((unsigned)(cy - gy0) <= (unsigned)dy)) {
            int s = atomicAdd(&gcnt_s, 1);
            if (s < GCAP) graw[s] = i8 * 8 + 2 * k + h;
          }
        }
      }
    }
    for (int g = (m8 << 3) + tid; g < M; g += 256) {  // tail (none for M=4096)
      unsigned u = gcb[g];
      int gx0 = (int)(u & 31u), dx = (int)((u >> 5) & 3u);
      int gy0 = (int)((u >> 7) & 31u), dy = (int)((u >> 12) & 3u);
      if (((unsigned)(cx - gx0) <= (unsigned)dx) & ((unsigned)(cy - gy0) <= (unsigned)dy)) {
        int s = atomicAdd(&gcnt_s, 1);
        if (s < GCAP) graw[s] = g;
      }
    }
  }
  __syncthreads();
  const int P = min(pcnt_s, PCAP);
  const int K = min(gcnt_s, GCAP);

  // rank-sort candidates ascending: deterministic accumulation order
  if (tid < K) {
    int v = graw[tid], rank = 0;
    for (int j = 0; j < K; ++j) rank += (graw[j] < v);
    gsrt[rank] = v;
  }
  __syncthreads();

  // Phase C: survivors only — exact IEEE voxelization + payload build.
  // Points on tid<128 (P<=128), gaussians on tid>=128 (K<=128): parallel halves.
  if (tid < P) {
    int i = lpi[tid];
    float px = pts[(size_t)i * 3], py = pts[(size_t)i * 3 + 1], pz = pts[(size_t)i * 3 + 2];
    int pvx = (int)floorf((px - PCXY) / GRIDSZ);
    int pvy = (int)floorf((py - PCXY) / GRIDSZ);
    int pvz = (int)floorf((pz - PCZ) / GRIDSZ);
    lvox[tid] = pvx | (pvy << 8) | (pvz << 16);
    lpts[tid] = make_float4(px, py, pz, __int_as_float(i));
  } else if (tid >= 128 && tid - 128 < K) {
    int t = tid - 128;
    int g = gsrt[t];
    float mx = means[(size_t)g * 3], my = means[(size_t)g * 3 + 1], mz = means[(size_t)g * 3 + 2];
    int mvx = (int)floorf((mx - PCXY) / GRIDSZ);
    int mvy = (int)floorf((my - PCXY) / GRIDSZ);
    int mvz = (int)floorf((mz - PCZ) / GRIDSZ);
    float sm = fmaxf(scales[(size_t)g * 3],
               fmaxf(scales[(size_t)g * 3 + 1], scales[(size_t)g * 3 + 2]));
    int r = (int)ceilf(sm * 3.0f / GRIDSZ);
    lbox[t] = make_int4(mvx - r, mvy - r, mvz - r, 2 * r);
    const float* c = cov + (size_t)g * 9;
    float c00 = c[0], c01 = c[1], c02 = c[2], c11 = c[4], c12 = c[5], c22 = c[8];
    float M00 = c11 * c22 - c12 * c12;
    float M01 = c02 * c12 - c01 * c22;
    float M02 = c01 * c12 - c02 * c11;
    float inv = 1.0f / (c00 * M00 + c01 * M01 + c02 * M02);
    lpay[t * 3 + 0] = make_float4(mx, my, mz, opac[g]);
    lpay[t * 3 + 1] = make_float4(M00 * inv, M01 * inv, M02 * inv,
                                  (c00 * c22 - c02 * c02) * inv);
    lpay[t * 3 + 2] = make_float4((c01 * c02 - c00 * c12) * inv,
                                  (c00 * c11 - c01 * c01) * inv, 0.f, 0.f);
  }
  for (int idx = tid; idx < K * CCH; idx += 256) {
    int j = idx / CCH, c2 = idx - j * CCH;
    lsem[j * SEMW + c2] = sem[(size_t)gsrt[j] * CCH + c2];
  }
  __syncthreads();

  // Phase D: dense point x candidate loop, wave-quartered.
  const int kq = (K + 3) >> 2;
  const int j0 = wave * kq, j1 = min(K, j0 + kq);

  for (int pb = 0; pb < P; pb += 64) {
    const bool vp = (pb + lane) < P;
    const float4 pt = lpts[vp ? pb + lane : 0];
    const int pv = vp ? lvox[pb + lane] : 0;
    int pvx = vp ? (pv & 255) : -100000;  // sentinel fails every box
    int pvy = (pv >> 8) & 255;
    int pvz = pv >> 16;

    float acc[CCH];
#pragma unroll
    for (int c = 0; c < CCH; ++c) acc[c] = 0.f;

    for (int j = j0; j < j1; ++j) {
      int4 bx = lbox[j];  // uniform -> LDS broadcast
      bool m = ((unsigned)(pvx - bx.x) <= (unsigned)bx.w) &
               ((unsigned)(pvy - bx.y) <= (unsigned)bx.w) &
               ((unsigned)(pvz - bx.z) <= (unsigned)bx.w);
      if (__any(m)) {
        float4 q0 = lpay[j * 3 + 0];
        float4 q1 = lpay[j * 3 + 1];
        float4 q2 = lpay[j * 3 + 2];
        float dx = pt.x - q0.x, dy = pt.y - q0.y, dz = pt.z - q0.z;
        float t0 = q1.x * dx + q1.y * dy + q1.z * dz;
        float t1 = q1.y * dx + q1.w * dy + q2.x * dz;
        float t2 = q1.z * dx + q2.x * dy + q2.y * dz;
        float qq = dx * t0 + dy * t1 + dz * t2;
        float w = m ? __expf(-0.5f * qq) * q0.w : 0.f;
        const float4* s4 = reinterpret_cast<const float4*>(&lsem[j * SEMW]);
        float4 sa = s4[0], sb = s4[1], sc = s4[2], sd = s4[3];
        float2 se = *reinterpret_cast<const float2*>(&lsem[j * SEMW + 16]);
        acc[0]  = fmaf(w, sa.x, acc[0]);  acc[1]  = fmaf(w, sa.y, acc[1]);
        acc[2]  = fmaf(w, sa.z, acc[2]);  acc[3]  = fmaf(w, sa.w, acc[3]);
        acc[4]  = fmaf(w, sb.x, acc[4]);  acc[5]  = fmaf(w, sb.y, acc[5]);
        acc[6]  = fmaf(w, sb.z, acc[6]);  acc[7]  = fmaf(w, sb.w, acc[7]);
        acc[8]  = fmaf(w, sc.x, acc[8]);  acc[9]  = fmaf(w, sc.y, acc[9]);
        acc[10] = fmaf(w, sc.z, acc[10]); acc[11] = fmaf(w, sc.w, acc[11]);
        acc[12] = fmaf(w, sd.x, acc[12]); acc[13] = fmaf(w, sd.y, acc[13]);
        acc[14] = fmaf(w, sd.z, acc[14]); acc[15] = fmaf(w, sd.w, acc[15]);
        acc[16] = fmaf(w, se.x, acc[16]); acc[17] = fmaf(w, se.y, acc[17]);
      }
    }

    // deterministic cross-wave reduce, one write per point
    if (wave > 0) {
#pragma unroll
      for (int c = 0; c < CCH; ++c) buf[wave - 1][lane][c] = acc[c];
    }
    __syncthreads();
    if (wave == 0 && vp) {
      int myp = __float_as_int(pt.w);
      float* o = out + (size_t)myp * CCH;
#pragma unroll
      for (int c = 0; c < CCH; ++c)
        o[c] = acc[c] + buf[0][lane][c] + buf[1][lane][c] + buf[2][lane][c];
    }
    __syncthreads();  // buf reused by next point-chunk
  }
}

extern "C" void kernel_launch(void* const* d_in, const int* in_sizes, int n_in,
                              void* d_out, int out_size, void* d_ws, size_t ws_size,
                              hipStream_t stream) {
  const float* pts     = (const float*)d_in[0];
  const float* means3D = (const float*)d_in[1];
  const float* opac    = (const float*)d_in[2];
  const float* sem     = (const float*)d_in[3];
  const float* scales  = (const float*)d_in[4];
  const float* cov3D   = (const float*)d_in[5];
  float* out = (float*)d_out;

  int N = in_sizes[0] / 3;
  int M = in_sizes[1] / 3;

  char* ws = (char*)d_ws;
  size_t off = 0;
  auto alloc = [&](size_t bytes) { char* p = ws + off; off = (off + bytes + 255) & ~(size_t)255; return p; };
  unsigned short* pcell = (unsigned short*)alloc((size_t)N * 2);
  unsigned short* gcb   = (unsigned short*)alloc((size_t)M * 2);

  prep_kernel<<<(N + M + 255) / 256, 256, 0, stream>>>(
      pts, means3D, scales, pcell, gcb, N, M);

  agg_kernel<<<NCELLS, 256, 0, stream>>>(
      pts, means3D, opac, scales, cov3D, sem, pcell, gcb, out, N, M);
}